// Round 5
// baseline (449.567 us; speedup 1.0000x reference)
//
#include <hip/hip_runtime.h>
#include <hip/hip_bf16.h>

#define NDIM 2048
#define BS   64
#define NM4  (NDIM * NDIM / 4)
#define BSN  ((size_t)BS * NDIM)

typedef __bf16 bf16_t;
typedef __bf16 bf16x4 __attribute__((ext_vector_type(4)));
typedef __bf16 bf16x8 __attribute__((ext_vector_type(8)));
typedef float  f32x4  __attribute__((ext_vector_type(4)));

// ---------------------------------------------------------------------------
// prep: convert H,U->bf16; transpose+convert Dinv,invM; y->bf16; zero traj[0].
// ---------------------------------------------------------------------------
__global__ __launch_bounds__(256) void prep(
    const float* __restrict__ H, const float* __restrict__ U,
    const float* __restrict__ Dinv, const float* __restrict__ invM,
    const float* __restrict__ y,
    bf16_t* __restrict__ H16, bf16_t* __restrict__ U16,
    bf16_t* __restrict__ Dt, bf16_t* __restrict__ iMt,
    bf16_t* __restrict__ y16, float* __restrict__ traj0) {
  __shared__ bf16_t tile[32][33];
  int b = blockIdx.x, tid = threadIdx.x;
  if (b < 8192) {
    int idx = b * 256 + tid;
    const float* src = (idx < NM4) ? H : U;
    bf16_t* dst = (idx < NM4) ? H16 : U16;
    int i = (idx < NM4) ? idx : idx - NM4;
    float4 v = ((const float4*)src)[i];
    bf16x4 o = {(bf16_t)v.x, (bf16_t)v.y, (bf16_t)v.z, (bf16_t)v.w};
    ((bf16x4*)dst)[i] = o;
    if (idx < BS * NDIM / 4) {
      float4 w = ((const float4*)y)[idx];
      bf16x4 o2 = {(bf16_t)w.x, (bf16_t)w.y, (bf16_t)w.z, (bf16_t)w.w};
      ((bf16x4*)y16)[idx] = o2;
      ((float4*)traj0)[idx] = make_float4(0.f, 0.f, 0.f, 0.f);
    }
  } else {
    int id = b - 8192;
    int bx = id & 63, by = id >> 6;
    int tx = tid & 31, ty = tid >> 5;
    const float* src[2] = {Dinv, invM};
    bf16_t* dst[2] = {Dt, iMt};
#pragma unroll
    for (int m = 0; m < 2; ++m) {
      __syncthreads();
#pragma unroll
      for (int i = 0; i < 4; ++i)
        tile[ty + i * 8][tx] =
            (bf16_t)src[m][(size_t)(by * 32 + ty + i * 8) * NDIM + bx * 32 + tx];
      __syncthreads();
#pragma unroll
      for (int i = 0; i < 4; ++i)
        dst[m][(size_t)(bx * 32 + ty + i * 8) * NDIM + by * 32 + tx] = tile[tx][ty + i * 8];
    }
  }
}

// ---------------------------------------------------------------------------
// Skinny NT GEMM role, K-chunked (32 KB LDS): C[64,16] = add + sign*(A@Bt^T).
// Panel in MFMA fragment order, staged in two K-halves of 1024.
// ---------------------------------------------------------------------------
__device__ __forceinline__ void skinny_role(
    const bf16_t* __restrict__ A, const bf16_t* __restrict__ Bt, int n0, char* smem,
    const float* __restrict__ add, float sign,
    float* o32, float* o32b, bf16_t* o16) {
  bf16x8* panel = (bf16x8*)smem;  // 2048 slots = 32 KB (16 cols x 1024 K)
  int tid = threadIdx.x, lane = tid & 63, wave = tid >> 6;
  int ml = lane & 15, q = lane >> 4;
  f32x4 acc[4];
  acc[0] = acc[1] = acc[2] = acc[3] = (f32x4){0.f, 0.f, 0.f, 0.f};
#pragma unroll
  for (int half = 0; half < 2; ++half) {
    __syncthreads();
#pragma unroll
    for (int i = 0; i < 8; ++i) {
      int F = i * 256 + tid, c = F >> 6, ln = F & 63;
      panel[F] = *(const bf16x8*)(Bt + (size_t)(n0 + (ln & 15)) * NDIM +
                                  half * 1024 + c * 32 + ((ln >> 4) << 3));
    }
    __syncthreads();
    const bf16x8* Ap = (const bf16x8*)(A + (size_t)(wave * 16 + ml) * NDIM) + q + half * 128;
    const bf16x8* Bp = panel + lane;
#pragma unroll 16
    for (int c = 0; c < 32; ++c) {
      bf16x8 a = Ap[c * 4];
      bf16x8 b = Bp[c * 64];
      acc[c & 3] = __builtin_amdgcn_mfma_f32_16x16x32_bf16(a, b, acc[c & 3], 0, 0, 0);
    }
  }
  f32x4 s = (acc[0] + acc[1]) + (acc[2] + acc[3]);
  int mrow = wave * 16 + q * 4, col = n0 + ml;
#pragma unroll
  for (int r = 0; r < 4; ++r) {
    size_t o = (size_t)(mrow + r) * NDIM + col;
    float v = sign * s[r];
    if (add) v += add[o];
    if (o32)  o32[o]  = v;
    if (o32b) o32b[o] = v;
    if (o16)  o16[o]  = (bf16_t)v;
  }
}

// ---------------------------------------------------------------------------
// 2048^3 NT GEMM role, 128x64 tile (12 KB LDS), BK=32, 8 MFMAs/K-step.
// blk in [0,512): m0 = (blk>>5)*128, n0 = (blk&31)*64.  Fragment-ordered LDS.
// ---------------------------------------------------------------------------
__device__ __forceinline__ void wgemm_role(
    const bf16_t* __restrict__ A, const bf16_t* __restrict__ Bt,
    bf16_t* __restrict__ C, int blk, char* smem) {
  bf16x8* As = (bf16x8*)smem;           // 512 slots (8 KB): 8 rowgroups x 64
  bf16x8* Bs = (bf16x8*)(smem + 8192);  // 256 slots (4 KB): 4 rowgroups x 64
  int tid = threadIdx.x, lane = tid & 63, wave = tid >> 6;
  int m0 = (blk >> 5) * 128, n0 = (blk & 31) * 64;
  int wr4 = (wave >> 1) * 4, wc2 = (wave & 1) * 2;  // rowgroup bases
  int ml = lane & 15, q = lane >> 4;

  f32x4 acc[4][2];
#pragma unroll
  for (int i = 0; i < 4; ++i)
#pragma unroll
    for (int j = 0; j < 2; ++j) acc[i][j] = (f32x4){0.f, 0.f, 0.f, 0.f};

  for (int k0 = 0; k0 < NDIM; k0 += 32) {
    __syncthreads();
#pragma unroll
    for (int i = 0; i < 2; ++i) {
      int S = i * 256 + tid, g = S >> 6, ln = S & 63;
      As[S] = *(const bf16x8*)(A + (size_t)(m0 + g * 16 + (ln & 15)) * NDIM + k0 + ((ln >> 4) << 3));
    }
    {
      int S = tid, g = S >> 6, ln = S & 63;
      Bs[S] = *(const bf16x8*)(Bt + (size_t)(n0 + g * 16 + (ln & 15)) * NDIM + k0 + ((ln >> 4) << 3));
    }
    __syncthreads();
    bf16x8 af[4], bfr[2];
#pragma unroll
    for (int i = 0; i < 4; ++i) af[i] = As[(wr4 + i) * 64 + lane];
#pragma unroll
    for (int j = 0; j < 2; ++j) bfr[j] = Bs[(wc2 + j) * 64 + lane];
#pragma unroll
    for (int i = 0; i < 4; ++i)
#pragma unroll
      for (int j = 0; j < 2; ++j)
        acc[i][j] = __builtin_amdgcn_mfma_f32_16x16x32_bf16(af[i], bfr[j], acc[i][j], 0, 0, 0);
  }
  int wr = wr4 * 16, wc = wc2 * 16;
#pragma unroll
  for (int i = 0; i < 4; ++i)
#pragma unroll
    for (int j = 0; j < 2; ++j)
#pragma unroll
      for (int r = 0; r < 4; ++r)
        C[(size_t)(m0 + wr + i * 16 + q * 4 + r) * NDIM + n0 + wc + j * 16 + ml] =
            (bf16_t)acc[i][j][r];
}

// ---------------------------------------------------------------------------
// 64x64-tile bf16 transpose role (dst = src^T).  blk in [0,1024).
// ---------------------------------------------------------------------------
__device__ __forceinline__ void transpose_role(const bf16_t* __restrict__ src,
                                               bf16_t* __restrict__ dst, int blk, char* smem) {
  bf16_t (*tile)[72] = (bf16_t(*)[72])smem;  // 9.2 KB
  int tid = threadIdx.x;
  int bx = blk & 31, by = blk >> 5;
#pragma unroll
  for (int i = 0; i < 2; ++i) {
    int v = i * 256 + tid, r = v >> 3, c8 = (v & 7) * 8;
    *(bf16x8*)&tile[r][c8] = *(const bf16x8*)(src + (size_t)(by * 64 + r) * NDIM + bx * 64 + c8);
  }
  __syncthreads();
#pragma unroll
  for (int i = 0; i < 2; ++i) {
    int v = i * 256 + tid, r = v >> 3, c8 = (v & 7) * 8;
    bf16x8 o;
#pragma unroll
    for (int j = 0; j < 8; ++j) o[j] = tile[c8 + j][r];
    *(bf16x8*)(dst + (size_t)(bx * 64 + r) * NDIM + by * 64 + c8) = o;
  }
}

// --------------------------- mega nodes ------------------------------------
// A: yMF = y@H^T (128) || Wrm = U@invM (512 wgemm)
__global__ __launch_bounds__(256) void megaA(
    const bf16_t* __restrict__ U16, const bf16_t* __restrict__ iMt16,
    const bf16_t* __restrict__ y16, const bf16_t* __restrict__ H16,
    bf16_t* __restrict__ Wrm, bf16_t* __restrict__ yMF16) {
  __shared__ char smem[32768];
  int b = blockIdx.x;
  if (b < 128) skinny_role(y16, H16, b * 16, smem, nullptr, 1.f, nullptr, nullptr, yMF16);
  else         wgemm_role(U16, iMt16, Wrm, b - 128, smem);
}

// B: Wt = Wrm^T (1024) || c = yMF@invM (128) || x0 = yMF@Dinv (128 -> z0 slot0)
__global__ __launch_bounds__(256) void megaB(
    const bf16_t* __restrict__ Wrm, const bf16_t* __restrict__ yMF16,
    const bf16_t* __restrict__ iMt16, const bf16_t* __restrict__ Dt16,
    bf16_t* __restrict__ Wt, float* __restrict__ c32, bf16_t* __restrict__ c16,
    bf16_t* __restrict__ z0) {
  __shared__ char smem[32768];
  int b = blockIdx.x;
  if (b < 1024)      transpose_role(Wrm, Wt, b, smem);
  else if (b < 1152) skinny_role(yMF16, iMt16, (b - 1024) * 16, smem, nullptr, 1.f, c32, nullptr, c16);
  else               skinny_role(yMF16, Dt16, (b - 1152) * 16, smem, nullptr, 1.f, nullptr, nullptr, z0);
}

// C: W2t = Wt@Wrm^T(NT) (512) || x1 = c - x0@W (128 -> traj[1], z0 slot1)
//    || c2 = c - c@W (128)
__global__ __launch_bounds__(256) void megaC(
    const bf16_t* __restrict__ Wt, const bf16_t* __restrict__ Wrm,
    const bf16_t* __restrict__ z0, const bf16_t* __restrict__ c16,
    const float* __restrict__ c32,
    bf16_t* __restrict__ W2t, float* __restrict__ traj1, bf16_t* __restrict__ z0b,
    float* __restrict__ c2_32, bf16_t* __restrict__ c2_16) {
  __shared__ char smem[32768];
  int b = blockIdx.x;
  if (b < 512)      wgemm_role(Wt, Wrm, W2t, b, smem);
  else if (b < 640) skinny_role(z0, Wt, (b - 512) * 16, smem, c32, -1.f, traj1, nullptr, z0b);
  else              skinny_role(c16, Wt, (b - 640) * 16, smem, c32, -1.f, c2_32, nullptr, c2_16);
}

// D: W2rm = W2t^T (1024) || x2 = c2+x0@W2 (128 -> traj[2], zA0)
//    || x3 = c2+x1@W2 (128 -> traj[3], zA1) || c4 = c2+c2@W2 (128)
__global__ __launch_bounds__(256) void megaD(
    const bf16_t* __restrict__ W2t, const bf16_t* __restrict__ z0,
    const bf16_t* __restrict__ c2_16, const float* __restrict__ c2_32,
    bf16_t* __restrict__ W2rm, float* __restrict__ traj2, float* __restrict__ traj3,
    bf16_t* __restrict__ zA, float* __restrict__ c4_32) {
  __shared__ char smem[32768];
  int b = blockIdx.x;
  if (b < 1024)      transpose_role(W2t, W2rm, b, smem);
  else if (b < 1152) skinny_role(z0, W2t, (b - 1024) * 16, smem, c2_32, 1.f, traj2, nullptr, zA);
  else if (b < 1280) skinny_role(z0 + BSN, W2t, (b - 1152) * 16, smem, c2_32, 1.f, traj3, nullptr, zA + BSN);
  else               skinny_role(c2_16, W2t, (b - 1280) * 16, smem, c2_32, 1.f, c4_32, nullptr, nullptr);
}

// E: W4t = W2t@W2rm^T(NT) (512) || x4 = c2+x2@W2 (128 -> traj[4], zA2)
//    || x5 = c2+x3@W2 (128 -> traj[5], zA3)
__global__ __launch_bounds__(256) void megaE(
    const bf16_t* __restrict__ W2t, const bf16_t* __restrict__ W2rm,
    const bf16_t* __restrict__ zA_in, const float* __restrict__ c2_32,
    bf16_t* __restrict__ W4t, float* __restrict__ traj4, float* __restrict__ traj5,
    bf16_t* __restrict__ zA) {
  __shared__ char smem[32768];
  int b = blockIdx.x;
  if (b < 512)      wgemm_role(W2t, W2rm, W4t, b, smem);
  else if (b < 640) skinny_role(zA_in, W2t, (b - 512) * 16, smem, c2_32, 1.f, traj4, nullptr, zA + 2 * BSN);
  else              skinny_role(zA_in + BSN, W2t, (b - 640) * 16, smem, c2_32, 1.f, traj5, nullptr, zA + 3 * BSN);
}

// Quad step: 4 chains x_{k+4} = c4 + x_k@W4.  512 blocks: chain b&3, panel b>>2.
__global__ __launch_bounds__(256) void quad_step(
    const bf16_t* __restrict__ zin, const bf16_t* __restrict__ W4t,
    const float* __restrict__ c4_32, float* __restrict__ trajb,
    bf16_t* __restrict__ zout, float* __restrict__ sfin) {
  __shared__ char smem[32768];
  int b = blockIdx.x, ci = b & 3, p = b >> 2;
  skinny_role(zin + (size_t)ci * BSN, W4t, p * 16, smem, c4_32, 1.f,
              trajb + (size_t)ci * BSN, (ci == 3) ? sfin : nullptr,
              zout + (size_t)ci * BSN);
}

// ---------------------------------------------------------------------------
// Host driver: 11 graph nodes.
// ---------------------------------------------------------------------------
extern "C" void kernel_launch(void* const* d_in, const int* in_sizes, int n_in,
                              void* d_out, int out_size, void* d_ws, size_t ws_size,
                              hipStream_t stream) {
  const float* y    = (const float*)d_in[2];
  const float* H    = (const float*)d_in[3];
  const float* Dinv = (const float*)d_in[4];
  const float* U    = (const float*)d_in[5];
  const float* invM = (const float*)d_in[6];

  float* out     = (float*)d_out;
  float* s_final = out;
  float* traj    = out + BSN;

  char* ws = (char*)d_ws;
  size_t off = 0;
  auto alloc = [&](size_t bytes) -> void* {
    void* p = ws + off;
    off += (bytes + 255) & ~(size_t)255;
    return p;
  };
  bf16_t* U16   = (bf16_t*)alloc((size_t)NDIM * NDIM * 2);  // -> W2rm after megaA
  bf16_t* Dt16  = (bf16_t*)alloc((size_t)NDIM * NDIM * 2);  // -> W4t after megaB
  bf16_t* iMt16 = (bf16_t*)alloc((size_t)NDIM * NDIM * 2);
  bf16_t* H16   = (bf16_t*)alloc((size_t)NDIM * NDIM * 2);  // -> W2t after megaA
  bf16_t* Wrm   = (bf16_t*)alloc((size_t)NDIM * NDIM * 2);
  bf16_t* Wt    = (bf16_t*)alloc((size_t)NDIM * NDIM * 2);
  bf16_t* y16   = (bf16_t*)alloc(BSN * 2);
  bf16_t* yMF16 = (bf16_t*)alloc(BSN * 2);
  bf16_t* c16   = (bf16_t*)alloc(BSN * 2);
  bf16_t* c2_16 = (bf16_t*)alloc(BSN * 2);
  float*  c32   = (float*)alloc(BSN * 4);
  float*  c2_32 = (float*)alloc(BSN * 4);
  float*  c4_32 = (float*)alloc(BSN * 4);
  bf16_t* z0    = (bf16_t*)alloc(2 * BSN * 2);  // x0, x1
  bf16_t* zA    = (bf16_t*)alloc(4 * BSN * 2);  // 4 chains
  bf16_t* zB    = (bf16_t*)alloc(4 * BSN * 2);
  bf16_t* W2t   = H16;   // H16 dead after megaA
  bf16_t* W2rm  = U16;   // U16 dead after megaA
  bf16_t* W4t   = Dt16;  // Dt16 dead after megaB

  // N1..N6: setup + seeds x0..x5 + W, W2, W4
  prep<<<12288, 256, 0, stream>>>(H, U, Dinv, invM, y, H16, U16, Dt16, iMt16, y16, traj);
  megaA<<<640, 256, 0, stream>>>(U16, iMt16, y16, H16, Wrm, yMF16);
  megaB<<<1280, 256, 0, stream>>>(Wrm, yMF16, iMt16, Dt16, Wt, c32, c16, z0);
  megaC<<<768, 256, 0, stream>>>(Wt, Wrm, z0, c16, c32, W2t, traj + BSN, z0 + BSN, c2_32, c2_16);
  megaD<<<1408, 256, 0, stream>>>(W2t, z0, c2_16, c2_32, W2rm, traj + 2 * BSN, traj + 3 * BSN,
                                  zA, c4_32);
  megaE<<<768, 256, 0, stream>>>(W2t, W2rm, zA, c2_32, W4t, traj + 4 * BSN, traj + 5 * BSN, zA);

  // N7..N11: 5 quad steps -> x6..x25
  bf16_t* zcur = zA;
  bf16_t* znxt = zB;
  for (int g = 0; g < 5; ++g) {
    float* sfin = (g == 4) ? s_final : nullptr;
    quad_step<<<512, 256, 0, stream>>>(zcur, W4t, c4_32, traj + (size_t)(6 + 4 * g) * BSN,
                                       znxt, sfin);
    bf16_t* tmp = zcur; zcur = znxt; znxt = tmp;
  }
}

// Round 6
// 419.784 us; speedup vs baseline: 1.0709x; 1.0709x over previous
//
#include <hip/hip_runtime.h>
#include <hip/hip_bf16.h>

#define NDIM 2048
#define BS   64
#define NM4  (NDIM * NDIM / 4)
#define BSN  ((size_t)BS * NDIM)
#define SMEM_BYTES 69632   // 64 KB panel/exchange + 4 KB reduction scratch

typedef __bf16 bf16_t;
typedef __bf16 bf16x4 __attribute__((ext_vector_type(4)));
typedef __bf16 bf16x8 __attribute__((ext_vector_type(8)));
typedef float  f32x4  __attribute__((ext_vector_type(4)));

// ---------------------------------------------------------------------------
// prep (256 thr): convert H,U->bf16; transpose+convert Dinv,invM; y; traj[0]=0.
// ---------------------------------------------------------------------------
__global__ __launch_bounds__(256) void prep(
    const float* __restrict__ H, const float* __restrict__ U,
    const float* __restrict__ Dinv, const float* __restrict__ invM,
    const float* __restrict__ y,
    bf16_t* __restrict__ H16, bf16_t* __restrict__ U16,
    bf16_t* __restrict__ Dt, bf16_t* __restrict__ iMt,
    bf16_t* __restrict__ y16, float* __restrict__ traj0) {
  __shared__ bf16_t tile[32][33];
  int b = blockIdx.x, tid = threadIdx.x;
  if (b < 8192) {
    int idx = b * 256 + tid;
    const float* src = (idx < NM4) ? H : U;
    bf16_t* dst = (idx < NM4) ? H16 : U16;
    int i = (idx < NM4) ? idx : idx - NM4;
    float4 v = ((const float4*)src)[i];
    bf16x4 o = {(bf16_t)v.x, (bf16_t)v.y, (bf16_t)v.z, (bf16_t)v.w};
    ((bf16x4*)dst)[i] = o;
    if (idx < BS * NDIM / 4) {
      float4 w = ((const float4*)y)[idx];
      bf16x4 o2 = {(bf16_t)w.x, (bf16_t)w.y, (bf16_t)w.z, (bf16_t)w.w};
      ((bf16x4*)y16)[idx] = o2;
      ((float4*)traj0)[idx] = make_float4(0.f, 0.f, 0.f, 0.f);
    }
  } else {
    int id = b - 8192;
    int bx = id & 63, by = id >> 6;
    int tx = tid & 31, ty = tid >> 5;
    const float* src[2] = {Dinv, invM};
    bf16_t* dst[2] = {Dt, iMt};
#pragma unroll
    for (int m = 0; m < 2; ++m) {
      __syncthreads();
#pragma unroll
      for (int i = 0; i < 4; ++i)
        tile[ty + i * 8][tx] =
            (bf16_t)src[m][(size_t)(by * 32 + ty + i * 8) * NDIM + bx * 32 + tx];
      __syncthreads();
#pragma unroll
      for (int i = 0; i < 4; ++i)
        dst[m][(size_t)(bx * 32 + ty + i * 8) * NDIM + by * 32 + tx] = tile[tx][ty + i * 8];
    }
  }
}

// ---------------------------------------------------------------------------
// 2048^3 NT GEMM role, 512 thr, 128x128 tile, IN-BLOCK SPLIT-K x2:
// waves 0-3 = K[0,1024), waves 4-7 = K[1024,2048), same tile quadrant per
// (wave&3).  BK=32; 4 staging buffers (lo/hi x A/B) 32 KB; fp32 LDS exchange
// (64 KB, overlays staging) joins the halves.  Fragment-ordered LDS, zero
// bank conflicts; exchange slots lane-consecutive.
// ---------------------------------------------------------------------------
__device__ __forceinline__ void wgemm_role(
    const bf16_t* __restrict__ A, const bf16_t* __restrict__ Bt,
    bf16_t* __restrict__ C, int blk, char* smem) {
  bf16x8* As_lo = (bf16x8*)smem;
  bf16x8* Bs_lo = (bf16x8*)(smem + 8192);
  bf16x8* As_hi = (bf16x8*)(smem + 16384);
  bf16x8* Bs_hi = (bf16x8*)(smem + 24576);
  int tid = threadIdx.x, lane = tid & 63, wave = tid >> 6;
  int kh = wave >> 2, wq = wave & 3;
  int m0 = (blk >> 4) * 128, n0 = (blk & 15) * 128;
  int wr16 = (wq >> 1) * 4, wc16 = (wq & 1) * 4;  // rowgroup bases (units of 16 rows)
  int ml = lane & 15, q = lane >> 4;

  f32x4 acc[4][4];
#pragma unroll
  for (int i = 0; i < 4; ++i)
#pragma unroll
    for (int j = 0; j < 4; ++j) acc[i][j] = (f32x4){0.f, 0.f, 0.f, 0.f};

  // per-thread staging slot (fragment order): S = tid
  int sg = tid >> 6, sln = tid & 63;
  int srow = sg * 16 + (sln & 15), skq = (sln >> 4) << 3;

  for (int k0 = 0; k0 < 1024; k0 += 32) {
    __syncthreads();
    As_lo[tid] = *(const bf16x8*)(A  + (size_t)(m0 + srow) * NDIM + k0 + skq);
    Bs_lo[tid] = *(const bf16x8*)(Bt + (size_t)(n0 + srow) * NDIM + k0 + skq);
    As_hi[tid] = *(const bf16x8*)(A  + (size_t)(m0 + srow) * NDIM + 1024 + k0 + skq);
    Bs_hi[tid] = *(const bf16x8*)(Bt + (size_t)(n0 + srow) * NDIM + 1024 + k0 + skq);
    __syncthreads();
    bf16x8* Asb = kh ? As_hi : As_lo;
    bf16x8* Bsb = kh ? Bs_hi : Bs_lo;
    bf16x8 af[4], bfr[4];
#pragma unroll
    for (int i = 0; i < 4; ++i) {
      af[i]  = Asb[(wr16 + i) * 64 + lane];
      bfr[i] = Bsb[(wc16 + i) * 64 + lane];
    }
#pragma unroll
    for (int i = 0; i < 4; ++i)
#pragma unroll
      for (int j = 0; j < 4; ++j)
        acc[i][j] = __builtin_amdgcn_mfma_f32_16x16x32_bf16(af[i], bfr[j], acc[i][j], 0, 0, 0);
  }

  // join K-halves: upper waves dump, lower waves add.
  f32x4* exch = (f32x4*)smem;  // 4096 slots = 64 KB
  __syncthreads();
  if (kh == 1) {
#pragma unroll
    for (int f = 0; f < 16; ++f)
      exch[(f * 4 + wq) * 64 + lane] = acc[f >> 2][f & 3];
  }
  __syncthreads();
  if (kh == 0) {
    int wr = wr16 * 16, wc = wc16 * 16;
#pragma unroll
    for (int i = 0; i < 4; ++i)
#pragma unroll
      for (int j = 0; j < 4; ++j) {
        f32x4 s = acc[i][j] + exch[((i * 4 + j) * 4 + wq) * 64 + lane];
#pragma unroll
        for (int r = 0; r < 4; ++r)
          C[(size_t)(m0 + wr + i * 16 + q * 4 + r) * NDIM + n0 + wc + j * 16 + ml] =
              (bf16_t)s[r];
      }
  }
}

// ---------------------------------------------------------------------------
// Skinny NT GEMM role, 512 thr (round-3-verified form): C[64,16] =
// add + sign*(A[64,2048] @ Bt^T).  Waves 0-3: M-stripes K-half0; waves 4-7:
// K-half1; LDS f32x4 reduction.  64 KB fragment-ordered panel.
// ---------------------------------------------------------------------------
__device__ __forceinline__ void skinny_role(
    const bf16_t* __restrict__ A, const bf16_t* __restrict__ Bt, int n0, char* smem,
    const float* __restrict__ add, float sign,
    float* o32, float* o32b, bf16_t* o16) {
  bf16x8* panel = (bf16x8*)smem;            // 4096 slots = 64 KB
  f32x4* red = (f32x4*)(smem + 65536);      // 256 slots = 4 KB
  int tid = threadIdx.x, lane = tid & 63, wave = tid >> 6;
#pragma unroll
  for (int i = 0; i < 8; ++i) {
    int F = i * 512 + tid, c = F >> 6, ln = F & 63;
    panel[F] = *(const bf16x8*)(Bt + (size_t)(n0 + (ln & 15)) * NDIM + c * 32 + ((ln >> 4) << 3));
  }
  __syncthreads();

  int ms = (wave & 3) * 16, kh = wave >> 2;
  int ml = lane & 15, q = lane >> 4;
  const bf16x8* Ap = (const bf16x8*)(A + (size_t)(ms + ml) * NDIM) + q + kh * 128;
  const bf16x8* Bp = panel + lane + kh * 2048;

  f32x4 acc[4];
  acc[0] = acc[1] = acc[2] = acc[3] = (f32x4){0.f, 0.f, 0.f, 0.f};
#pragma unroll
  for (int c = 0; c < 32; ++c) {
    bf16x8 a = Ap[c * 4];
    bf16x8 b = Bp[c * 64];
    acc[c & 3] = __builtin_amdgcn_mfma_f32_16x16x32_bf16(a, b, acc[c & 3], 0, 0, 0);
  }
  f32x4 s = (acc[0] + acc[1]) + (acc[2] + acc[3]);

  if (wave >= 4) red[(wave & 3) * 64 + lane] = s;
  __syncthreads();
  if (wave < 4) {
    s += red[wave * 64 + lane];
    int mrow = ms + q * 4, col = n0 + ml;
#pragma unroll
    for (int r = 0; r < 4; ++r) {
      size_t o = (size_t)(mrow + r) * NDIM + col;
      float v = sign * s[r];
      if (add) v += add[o];
      if (o32)  o32[o]  = v;
      if (o32b) o32b[o] = v;
      if (o16)  o16[o]  = (bf16_t)v;
    }
  }
}

// ---------------------------------------------------------------------------
// 64x64-tile bf16 transpose role, 512 thr (dst = src^T).  blk in [0,1024).
// ---------------------------------------------------------------------------
__device__ __forceinline__ void transpose_role(const bf16_t* __restrict__ src,
                                               bf16_t* __restrict__ dst, int blk, char* smem) {
  bf16_t (*tile)[72] = (bf16_t(*)[72])smem;  // 9.2 KB
  int tid = threadIdx.x;
  int bx = blk & 31, by = blk >> 5;
  {
    int r = tid >> 3, c8 = (tid & 7) * 8;
    *(bf16x8*)&tile[r][c8] = *(const bf16x8*)(src + (size_t)(by * 64 + r) * NDIM + bx * 64 + c8);
  }
  __syncthreads();
  {
    int r = tid >> 3, c8 = (tid & 7) * 8;
    bf16x8 o;
#pragma unroll
    for (int j = 0; j < 8; ++j) o[j] = tile[c8 + j][r];
    *(bf16x8*)(dst + (size_t)(bx * 64 + r) * NDIM + by * 64 + c8) = o;
  }
}

// --------------------------- mega nodes (all 512 thr) ----------------------
// A: Wrm = U@invM (256 wgemm) || yMF = y@H^T (128 skinny)
__global__ __launch_bounds__(512, 2) void megaA(
    const bf16_t* __restrict__ U16, const bf16_t* __restrict__ iMt16,
    const bf16_t* __restrict__ y16, const bf16_t* __restrict__ H16,
    bf16_t* __restrict__ Wrm, bf16_t* __restrict__ yMF16) {
  __shared__ char smem[SMEM_BYTES];
  int b = blockIdx.x;
  if (b < 256) wgemm_role(U16, iMt16, Wrm, b, smem);
  else         skinny_role(y16, H16, (b - 256) * 16, smem, nullptr, 1.f, nullptr, nullptr, yMF16);
}

// B: Wt = Wrm^T (1024) || c = yMF@invM (128) || x0 = yMF@Dinv (128 -> z0)
__global__ __launch_bounds__(512, 2) void megaB(
    const bf16_t* __restrict__ Wrm, const bf16_t* __restrict__ yMF16,
    const bf16_t* __restrict__ iMt16, const bf16_t* __restrict__ Dt16,
    bf16_t* __restrict__ Wt, float* __restrict__ c32, bf16_t* __restrict__ c16,
    bf16_t* __restrict__ z0) {
  __shared__ char smem[SMEM_BYTES];
  int b = blockIdx.x;
  if (b < 1024)      transpose_role(Wrm, Wt, b, smem);
  else if (b < 1152) skinny_role(yMF16, iMt16, (b - 1024) * 16, smem, nullptr, 1.f, c32, nullptr, c16);
  else               skinny_role(yMF16, Dt16, (b - 1152) * 16, smem, nullptr, 1.f, nullptr, nullptr, z0);
}

// C: W2t = Wt@Wrm^T(NT) (256) || x1 = c - x0@W (128 -> traj[1], z0+BSN) || c2 (128)
__global__ __launch_bounds__(512, 2) void megaC(
    const bf16_t* __restrict__ Wt, const bf16_t* __restrict__ Wrm,
    const bf16_t* __restrict__ z0, const bf16_t* __restrict__ c16,
    const float* __restrict__ c32,
    bf16_t* __restrict__ W2t, float* __restrict__ traj1, bf16_t* __restrict__ z0b,
    float* __restrict__ c2_32, bf16_t* __restrict__ c2_16) {
  __shared__ char smem[SMEM_BYTES];
  int b = blockIdx.x;
  if (b < 256)      wgemm_role(Wt, Wrm, W2t, b, smem);
  else if (b < 384) skinny_role(z0, Wt, (b - 256) * 16, smem, c32, -1.f, traj1, nullptr, z0b);
  else              skinny_role(c16, Wt, (b - 384) * 16, smem, c32, -1.f, c2_32, nullptr, c2_16);
}

// D: W2rm = W2t^T (1024) || x2 (128 -> traj[2], zA0) || x3 (128 -> traj[3], zA1)
//    || c4 = c2 + c2@W2 (128)
__global__ __launch_bounds__(512, 2) void megaD(
    const bf16_t* __restrict__ W2t, const bf16_t* __restrict__ z0,
    const bf16_t* __restrict__ c2_16, const float* __restrict__ c2_32,
    bf16_t* __restrict__ W2rm, float* __restrict__ traj2, float* __restrict__ traj3,
    bf16_t* __restrict__ zA, float* __restrict__ c4_32) {
  __shared__ char smem[SMEM_BYTES];
  int b = blockIdx.x;
  if (b < 1024)      transpose_role(W2t, W2rm, b, smem);
  else if (b < 1152) skinny_role(z0, W2t, (b - 1024) * 16, smem, c2_32, 1.f, traj2, nullptr, zA);
  else if (b < 1280) skinny_role(z0 + BSN, W2t, (b - 1152) * 16, smem, c2_32, 1.f, traj3, nullptr, zA + BSN);
  else               skinny_role(c2_16, W2t, (b - 1280) * 16, smem, c2_32, 1.f, c4_32, nullptr, nullptr);
}

// E: W4t = W2t@W2rm^T(NT) (256) || x4 (128 -> traj[4], zA2) || x5 (128 -> traj[5], zA3)
__global__ __launch_bounds__(512, 2) void megaE(
    const bf16_t* __restrict__ W2t, const bf16_t* __restrict__ W2rm,
    const bf16_t* __restrict__ zA_in, const float* __restrict__ c2_32,
    bf16_t* __restrict__ W4t, float* __restrict__ traj4, float* __restrict__ traj5,
    bf16_t* __restrict__ zA) {
  __shared__ char smem[SMEM_BYTES];
  int b = blockIdx.x;
  if (b < 256)      wgemm_role(W2t, W2rm, W4t, b, smem);
  else if (b < 384) skinny_role(zA_in, W2t, (b - 256) * 16, smem, c2_32, 1.f, traj4, nullptr, zA + 2 * BSN);
  else              skinny_role(zA_in + BSN, W2t, (b - 384) * 16, smem, c2_32, 1.f, traj5, nullptr, zA + 3 * BSN);
}

// Quad step: 4 chains x_{k+4} = c4 + x_k@W4.  512 blocks: chain b&3, panel b>>2.
__global__ __launch_bounds__(512, 2) void quad_step(
    const bf16_t* __restrict__ zin, const bf16_t* __restrict__ W4t,
    const float* __restrict__ c4_32, float* __restrict__ trajb,
    bf16_t* __restrict__ zout, float* __restrict__ sfin) {
  __shared__ char smem[SMEM_BYTES];
  int b = blockIdx.x, ci = b & 3, p = b >> 2;
  skinny_role(zin + (size_t)ci * BSN, W4t, p * 16, smem, c4_32, 1.f,
              trajb + (size_t)ci * BSN, (ci == 3) ? sfin : nullptr,
              zout + (size_t)ci * BSN);
}

// ---------------------------------------------------------------------------
// Host driver: 11 graph nodes.
// ---------------------------------------------------------------------------
extern "C" void kernel_launch(void* const* d_in, const int* in_sizes, int n_in,
                              void* d_out, int out_size, void* d_ws, size_t ws_size,
                              hipStream_t stream) {
  const float* y    = (const float*)d_in[2];
  const float* H    = (const float*)d_in[3];
  const float* Dinv = (const float*)d_in[4];
  const float* U    = (const float*)d_in[5];
  const float* invM = (const float*)d_in[6];

  float* out     = (float*)d_out;
  float* s_final = out;
  float* traj    = out + BSN;

  char* ws = (char*)d_ws;
  size_t off = 0;
  auto alloc = [&](size_t bytes) -> void* {
    void* p = ws + off;
    off += (bytes + 255) & ~(size_t)255;
    return p;
  };
  bf16_t* U16   = (bf16_t*)alloc((size_t)NDIM * NDIM * 2);  // -> W2rm after megaA
  bf16_t* Dt16  = (bf16_t*)alloc((size_t)NDIM * NDIM * 2);  // -> W4t after megaB
  bf16_t* iMt16 = (bf16_t*)alloc((size_t)NDIM * NDIM * 2);
  bf16_t* H16   = (bf16_t*)alloc((size_t)NDIM * NDIM * 2);  // -> W2t after megaA
  bf16_t* Wrm   = (bf16_t*)alloc((size_t)NDIM * NDIM * 2);
  bf16_t* Wt    = (bf16_t*)alloc((size_t)NDIM * NDIM * 2);
  bf16_t* y16   = (bf16_t*)alloc(BSN * 2);
  bf16_t* yMF16 = (bf16_t*)alloc(BSN * 2);
  bf16_t* c16   = (bf16_t*)alloc(BSN * 2);
  bf16_t* c2_16 = (bf16_t*)alloc(BSN * 2);
  float*  c32   = (float*)alloc(BSN * 4);
  float*  c2_32 = (float*)alloc(BSN * 4);
  float*  c4_32 = (float*)alloc(BSN * 4);
  bf16_t* z0    = (bf16_t*)alloc(2 * BSN * 2);  // x0, x1
  bf16_t* zA    = (bf16_t*)alloc(4 * BSN * 2);  // chains x2..x5
  bf16_t* zB    = (bf16_t*)alloc(4 * BSN * 2);
  bf16_t* W2t   = H16;   // H16 dead after megaA
  bf16_t* W2rm  = U16;   // U16 dead after megaA
  bf16_t* W4t   = Dt16;  // Dt16 dead after megaB

  prep<<<12288, 256, 0, stream>>>(H, U, Dinv, invM, y, H16, U16, Dt16, iMt16, y16, traj);
  megaA<<<384, 512, 0, stream>>>(U16, iMt16, y16, H16, Wrm, yMF16);
  megaB<<<1280, 512, 0, stream>>>(Wrm, yMF16, iMt16, Dt16, Wt, c32, c16, z0);
  megaC<<<512, 512, 0, stream>>>(Wt, Wrm, z0, c16, c32, W2t, traj + BSN, z0 + BSN, c2_32, c2_16);
  megaD<<<1408, 512, 0, stream>>>(W2t, z0, c2_16, c2_32, W2rm, traj + 2 * BSN, traj + 3 * BSN,
                                  zA, c4_32);
  megaE<<<512, 512, 0, stream>>>(W2t, W2rm, zA, c2_32, W4t, traj + 4 * BSN, traj + 5 * BSN, zA);

  bf16_t* zcur = zA;
  bf16_t* znxt = zB;
  for (int g = 0; g < 5; ++g) {
    float* sfin = (g == 4) ? s_final : nullptr;
    quad_step<<<512, 512, 0, stream>>>(zcur, W4t, c4_32, traj + (size_t)(6 + 4 * g) * BSN,
                                       znxt, sfin);
    bf16_t* tmp = zcur; zcur = znxt; znxt = tmp;
  }
}

// Round 7
// 389.181 us; speedup vs baseline: 1.1552x; 1.0786x over previous
//
#include <hip/hip_runtime.h>
#include <hip/hip_bf16.h>

#define NDIM 2048
#define BS   64
#define NM4  (NDIM * NDIM / 4)
#define BSN  ((size_t)BS * NDIM)
#define SMEM_BYTES 69632   // wgemm: 4x16KB pipeline; skinny: 64KB panel + 4KB red

typedef __bf16 bf16_t;
typedef __bf16 bf16x4 __attribute__((ext_vector_type(4)));
typedef __bf16 bf16x8 __attribute__((ext_vector_type(8)));
typedef float  f32x4  __attribute__((ext_vector_type(4)));

// Async global->LDS, 16 B per lane.  LDS dest = wave-uniform base + lane*16.
__device__ __forceinline__ void gload16(const void* g, void* lds) {
  __builtin_amdgcn_global_load_lds(
      (const __attribute__((address_space(1))) void*)g,
      (__attribute__((address_space(3))) void*)lds, 16, 0, 0);
}

#define WB4 asm volatile("s_waitcnt vmcnt(4)\n\ts_barrier" ::: "memory")
#define WB2 asm volatile("s_waitcnt vmcnt(2)\n\ts_barrier" ::: "memory")
#define WB0 asm volatile("s_waitcnt vmcnt(0)\n\ts_barrier" ::: "memory")

// ---------------------------------------------------------------------------
// prep (512 thr, 3072 blocks): b<1024 convert H,U (+y, traj0); else 64x64
// fp32->bf16 vectorized transposes of Dinv, invM.
// ---------------------------------------------------------------------------
__global__ __launch_bounds__(512) void prep(
    const float* __restrict__ H, const float* __restrict__ U,
    const float* __restrict__ Dinv, const float* __restrict__ invM,
    const float* __restrict__ y,
    bf16_t* __restrict__ H16, bf16_t* __restrict__ U16,
    bf16_t* __restrict__ Dt, bf16_t* __restrict__ iMt,
    bf16_t* __restrict__ y16, float* __restrict__ traj0) {
  __shared__ bf16_t tile[64][72];
  int b = blockIdx.x, tid = threadIdx.x;
  if (b < 1024) {
#pragma unroll
    for (int i = 0; i < 4; ++i) {
      int idx = b * 2048 + i * 512 + tid;
      const float* src = (idx < NM4) ? H : U;
      bf16_t* dst = (idx < NM4) ? H16 : U16;
      int j = (idx < NM4) ? idx : idx - NM4;
      float4 v = ((const float4*)src)[j];
      bf16x4 o = {(bf16_t)v.x, (bf16_t)v.y, (bf16_t)v.z, (bf16_t)v.w};
      ((bf16x4*)dst)[j] = o;
    }
    int yi = b * 512 + tid;
    if (yi < BS * NDIM / 4) {
      float4 w = ((const float4*)y)[yi];
      bf16x4 o2 = {(bf16_t)w.x, (bf16_t)w.y, (bf16_t)w.z, (bf16_t)w.w};
      ((bf16x4*)y16)[yi] = o2;
      ((float4*)traj0)[yi] = make_float4(0.f, 0.f, 0.f, 0.f);
    }
  } else {
    int id = b - 1024;
    const float* src = (id < 1024) ? Dinv : invM;
    bf16_t* dst = (id < 1024) ? Dt : iMt;
    id &= 1023;
    int bx = id & 31, by = id >> 5;
    int r = tid >> 3, c8 = (tid & 7) * 8;
    const float* sp = src + (size_t)(by * 64 + r) * NDIM + bx * 64 + c8;
    float4 v0 = *(const float4*)sp;
    float4 v1 = *(const float4*)(sp + 4);
    bf16_t* t = &tile[r][c8];
    t[0] = (bf16_t)v0.x; t[1] = (bf16_t)v0.y; t[2] = (bf16_t)v0.z; t[3] = (bf16_t)v0.w;
    t[4] = (bf16_t)v1.x; t[5] = (bf16_t)v1.y; t[6] = (bf16_t)v1.z; t[7] = (bf16_t)v1.w;
    __syncthreads();
    bf16x8 o;
#pragma unroll
    for (int j = 0; j < 8; ++j) o[j] = tile[c8 + j][r];
    *(bf16x8*)(dst + (size_t)(bx * 64 + r) * NDIM + by * 64 + c8) = o;
  }
}

// ---------------------------------------------------------------------------
// wgemm v3: 2048^3 NT GEMM role, 512 thr, 128x128 tile, BK=32, 64 K-chunks,
// 4-stage async pipeline (global_load_lds + raw s_waitcnt vmcnt(4)/s_barrier
// so prefetches stay in flight across barriers).  Fragment-ordered LDS.
// Wave w: M-rowgroups (w&3)*2..+2, N-rowgroups (w>>2)*4..+4 (8 MFMA/chunk).
// ---------------------------------------------------------------------------
__device__ __forceinline__ void wgemm_role(
    const bf16_t* __restrict__ A, const bf16_t* __restrict__ Bt,
    bf16_t* __restrict__ C, int blk, char* smem) {
  int tid = threadIdx.x, lane = tid & 63, wave = tid >> 6;
  int m0 = (blk >> 4) * 128, n0 = (blk & 15) * 128;
  int rl = lane & 15, q = lane >> 4;
  const bf16_t* Ag = A  + (size_t)(m0 + wave * 16 + rl) * NDIM + q * 8;
  const bf16_t* Bg = Bt + (size_t)(n0 + wave * 16 + rl) * NDIM + q * 8;
  char* ldsA = smem + wave * 1024;
  char* ldsB = smem + 8192 + wave * 1024;

  f32x4 acc[2][4];
#pragma unroll
  for (int i = 0; i < 2; ++i)
#pragma unroll
    for (int j = 0; j < 4; ++j) acc[i][j] = (f32x4){0.f, 0.f, 0.f, 0.f};

  int wr2 = (wave & 3) * 2, wc4 = (wave >> 2) * 4;

#define STAGE(s)                                  \
  {                                               \
    int _b = (s) & 3, _k = (s) * 32;              \
    gload16(Ag + _k, ldsA + _b * 16384);          \
    gload16(Bg + _k, ldsB + _b * 16384);          \
  }
#define COMPUTE(bb)                                                            \
  {                                                                            \
    bf16x8* As = (bf16x8*)(smem + (bb) * 16384);                               \
    bf16x8* Bs = (bf16x8*)(smem + (bb) * 16384 + 8192);                        \
    bf16x8 af0 = As[wr2 * 64 + lane];                                          \
    bf16x8 af1 = As[(wr2 + 1) * 64 + lane];                                    \
    bf16x8 bf0 = Bs[wc4 * 64 + lane];                                          \
    bf16x8 bf1 = Bs[(wc4 + 1) * 64 + lane];                                    \
    bf16x8 bf2 = Bs[(wc4 + 2) * 64 + lane];                                    \
    bf16x8 bf3 = Bs[(wc4 + 3) * 64 + lane];                                    \
    acc[0][0] = __builtin_amdgcn_mfma_f32_16x16x32_bf16(af0, bf0, acc[0][0], 0, 0, 0); \
    acc[0][1] = __builtin_amdgcn_mfma_f32_16x16x32_bf16(af0, bf1, acc[0][1], 0, 0, 0); \
    acc[0][2] = __builtin_amdgcn_mfma_f32_16x16x32_bf16(af0, bf2, acc[0][2], 0, 0, 0); \
    acc[0][3] = __builtin_amdgcn_mfma_f32_16x16x32_bf16(af0, bf3, acc[0][3], 0, 0, 0); \
    acc[1][0] = __builtin_amdgcn_mfma_f32_16x16x32_bf16(af1, bf0, acc[1][0], 0, 0, 0); \
    acc[1][1] = __builtin_amdgcn_mfma_f32_16x16x32_bf16(af1, bf1, acc[1][1], 0, 0, 0); \
    acc[1][2] = __builtin_amdgcn_mfma_f32_16x16x32_bf16(af1, bf2, acc[1][2], 0, 0, 0); \
    acc[1][3] = __builtin_amdgcn_mfma_f32_16x16x32_bf16(af1, bf3, acc[1][3], 0, 0, 0); \
  }

  STAGE(0); STAGE(1); STAGE(2);
  int s = 3;
#pragma unroll 1
  for (int k = 0; k < 60; k += 4) {
    WB4; STAGE(s); ++s; COMPUTE(0);
    WB4; STAGE(s); ++s; COMPUTE(1);
    WB4; STAGE(s); ++s; COMPUTE(2);
    WB4; STAGE(s); ++s; COMPUTE(3);
  }
  WB4; STAGE(63); COMPUTE(0);   // k=60
  WB4; COMPUTE(1);              // k=61
  WB2; COMPUTE(2);              // k=62
  WB0; COMPUTE(3);              // k=63
#undef STAGE
#undef COMPUTE

#pragma unroll
  for (int i = 0; i < 2; ++i)
#pragma unroll
    for (int j = 0; j < 4; ++j)
#pragma unroll
      for (int r = 0; r < 4; ++r)
        C[(size_t)(m0 + (wr2 + i) * 16 + q * 4 + r) * NDIM + n0 + (wc4 + j) * 16 + rl] =
            (bf16_t)acc[i][j][r];
}

// ---------------------------------------------------------------------------
// skinny v3: C[64,16] = add + sign*(A[64,2048] @ Bt^T cols n0..+15).
// Panel (64 KB, fragment order) staged async; waves 0-3 K-half0 / 4-7 K-half1;
// 8 round-robin accumulators -> 8-deep global A-load pipelining; LDS f32
// reduction joins halves.
// ---------------------------------------------------------------------------
__device__ __forceinline__ void skinny_role(
    const bf16_t* __restrict__ A, const bf16_t* __restrict__ Bt, int n0, char* smem,
    const float* __restrict__ add, float sign,
    float* o32, float* o32b, bf16_t* o16) {
  int tid = threadIdx.x, lane = tid & 63, wave = tid >> 6;
  int rl = lane & 15, q = lane >> 4;
#pragma unroll
  for (int i = 0; i < 8; ++i) {
    const bf16_t* g = Bt + (size_t)(n0 + rl) * NDIM + (i * 8 + wave) * 32 + q * 8;
    gload16(g, smem + (size_t)(i * 512 + wave * 64) * 16);
  }
  __syncthreads();

  int ms = (wave & 3) * 16, kh = wave >> 2;
  const bf16x8* Ap = (const bf16x8*)(A + (size_t)(ms + rl) * NDIM) + q + kh * 128;
  const bf16x8* Bp = (const bf16x8*)smem + lane + kh * 2048;

  f32x4 acc[8];
#pragma unroll
  for (int i = 0; i < 8; ++i) acc[i] = (f32x4){0.f, 0.f, 0.f, 0.f};
#pragma unroll
  for (int c = 0; c < 32; ++c)
    acc[c & 7] = __builtin_amdgcn_mfma_f32_16x16x32_bf16(Ap[c * 4], Bp[c * 64], acc[c & 7], 0, 0, 0);
  f32x4 s = ((acc[0] + acc[1]) + (acc[2] + acc[3])) + ((acc[4] + acc[5]) + (acc[6] + acc[7]));

  f32x4* red = (f32x4*)(smem + 65536);
  if (wave >= 4) red[(wave & 3) * 64 + lane] = s;
  __syncthreads();
  if (wave < 4) {
    s += red[wave * 64 + lane];
    int mrow = ms + q * 4, col = n0 + rl;
#pragma unroll
    for (int r = 0; r < 4; ++r) {
      size_t o = (size_t)(mrow + r) * NDIM + col;
      float v = sign * s[r];
      if (add) v += add[o];
      if (o32)  o32[o]  = v;
      if (o32b) o32b[o] = v;
      if (o16)  o16[o]  = (bf16_t)v;
    }
  }
}

// ---------------------------------------------------------------------------
// 64x64-tile bf16 transpose role, 512 thr.  blk in [0,1024).
// ---------------------------------------------------------------------------
__device__ __forceinline__ void transpose_role(const bf16_t* __restrict__ src,
                                               bf16_t* __restrict__ dst, int blk, char* smem) {
  bf16_t (*tile)[72] = (bf16_t(*)[72])smem;
  int tid = threadIdx.x;
  int bx = blk & 31, by = blk >> 5;
  int r = tid >> 3, c8 = (tid & 7) * 8;
  *(bf16x8*)&tile[r][c8] = *(const bf16x8*)(src + (size_t)(by * 64 + r) * NDIM + bx * 64 + c8);
  __syncthreads();
  bf16x8 o;
#pragma unroll
  for (int j = 0; j < 8; ++j) o[j] = tile[c8 + j][r];
  *(bf16x8*)(dst + (size_t)(bx * 64 + r) * NDIM + by * 64 + c8) = o;
}

// --------------------------- mega nodes (512 thr) --------------------------
__global__ __launch_bounds__(512, 4) void megaA(
    const bf16_t* __restrict__ U16, const bf16_t* __restrict__ iMt16,
    const bf16_t* __restrict__ y16, const bf16_t* __restrict__ H16,
    bf16_t* __restrict__ Wrm, bf16_t* __restrict__ yMF16) {
  __shared__ char smem[SMEM_BYTES];
  int b = blockIdx.x;
  if (b < 256) wgemm_role(U16, iMt16, Wrm, b, smem);
  else         skinny_role(y16, H16, (b - 256) * 16, smem, nullptr, 1.f, nullptr, nullptr, yMF16);
}

__global__ __launch_bounds__(512, 4) void megaB(
    const bf16_t* __restrict__ Wrm, const bf16_t* __restrict__ yMF16,
    const bf16_t* __restrict__ iMt16, const bf16_t* __restrict__ Dt16,
    bf16_t* __restrict__ Wt, float* __restrict__ c32, bf16_t* __restrict__ c16,
    bf16_t* __restrict__ z0) {
  __shared__ char smem[SMEM_BYTES];
  int b = blockIdx.x;
  if (b < 1024)      transpose_role(Wrm, Wt, b, smem);
  else if (b < 1152) skinny_role(yMF16, iMt16, (b - 1024) * 16, smem, nullptr, 1.f, c32, nullptr, c16);
  else               skinny_role(yMF16, Dt16, (b - 1152) * 16, smem, nullptr, 1.f, nullptr, nullptr, z0);
}

__global__ __launch_bounds__(512, 4) void megaC(
    const bf16_t* __restrict__ Wt, const bf16_t* __restrict__ Wrm,
    const bf16_t* __restrict__ z0, const bf16_t* __restrict__ c16,
    const float* __restrict__ c32,
    bf16_t* __restrict__ W2t, float* __restrict__ traj1, bf16_t* __restrict__ z0b,
    float* __restrict__ c2_32, bf16_t* __restrict__ c2_16) {
  __shared__ char smem[SMEM_BYTES];
  int b = blockIdx.x;
  if (b < 256)      wgemm_role(Wt, Wrm, W2t, b, smem);
  else if (b < 384) skinny_role(z0, Wt, (b - 256) * 16, smem, c32, -1.f, traj1, nullptr, z0b);
  else              skinny_role(c16, Wt, (b - 384) * 16, smem, c32, -1.f, c2_32, nullptr, c2_16);
}

__global__ __launch_bounds__(512, 4) void megaD(
    const bf16_t* __restrict__ W2t, const bf16_t* __restrict__ z0,
    const bf16_t* __restrict__ c2_16, const float* __restrict__ c2_32,
    bf16_t* __restrict__ W2rm, float* __restrict__ traj2, float* __restrict__ traj3,
    bf16_t* __restrict__ zA, float* __restrict__ c4_32) {
  __shared__ char smem[SMEM_BYTES];
  int b = blockIdx.x;
  if (b < 1024)      transpose_role(W2t, W2rm, b, smem);
  else if (b < 1152) skinny_role(z0, W2t, (b - 1024) * 16, smem, c2_32, 1.f, traj2, nullptr, zA);
  else if (b < 1280) skinny_role(z0 + BSN, W2t, (b - 1152) * 16, smem, c2_32, 1.f, traj3, nullptr, zA + BSN);
  else               skinny_role(c2_16, W2t, (b - 1280) * 16, smem, c2_32, 1.f, c4_32, nullptr, nullptr);
}

__global__ __launch_bounds__(512, 4) void megaE(
    const bf16_t* __restrict__ W2t, const bf16_t* __restrict__ W2rm,
    const bf16_t* __restrict__ zA_in, const float* __restrict__ c2_32,
    bf16_t* __restrict__ W4t, float* __restrict__ traj4, float* __restrict__ traj5,
    bf16_t* __restrict__ zA) {
  __shared__ char smem[SMEM_BYTES];
  int b = blockIdx.x;
  if (b < 256)      wgemm_role(W2t, W2rm, W4t, b, smem);
  else if (b < 384) skinny_role(zA_in, W2t, (b - 256) * 16, smem, c2_32, 1.f, traj4, nullptr, zA + 2 * BSN);
  else              skinny_role(zA_in + BSN, W2t, (b - 384) * 16, smem, c2_32, 1.f, traj5, nullptr, zA + 3 * BSN);
}

__global__ __launch_bounds__(512, 4) void quad_step(
    const bf16_t* __restrict__ zin, const bf16_t* __restrict__ W4t,
    const float* __restrict__ c4_32, float* __restrict__ trajb,
    bf16_t* __restrict__ zout, float* __restrict__ sfin) {
  __shared__ char smem[SMEM_BYTES];
  int b = blockIdx.x, ci = b & 3, p = b >> 2;
  skinny_role(zin + (size_t)ci * BSN, W4t, p * 16, smem, c4_32, 1.f,
              trajb + (size_t)ci * BSN, (ci == 3) ? sfin : nullptr,
              zout + (size_t)ci * BSN);
}

// ---------------------------------------------------------------------------
// Host driver: 11 graph nodes.
// ---------------------------------------------------------------------------
extern "C" void kernel_launch(void* const* d_in, const int* in_sizes, int n_in,
                              void* d_out, int out_size, void* d_ws, size_t ws_size,
                              hipStream_t stream) {
  const float* y    = (const float*)d_in[2];
  const float* H    = (const float*)d_in[3];
  const float* Dinv = (const float*)d_in[4];
  const float* U    = (const float*)d_in[5];
  const float* invM = (const float*)d_in[6];

  float* out     = (float*)d_out;
  float* s_final = out;
  float* traj    = out + BSN;

  char* ws = (char*)d_ws;
  size_t off = 0;
  auto alloc = [&](size_t bytes) -> void* {
    void* p = ws + off;
    off += (bytes + 255) & ~(size_t)255;
    return p;
  };
  bf16_t* U16   = (bf16_t*)alloc((size_t)NDIM * NDIM * 2);  // -> W2rm after megaA
  bf16_t* Dt16  = (bf16_t*)alloc((size_t)NDIM * NDIM * 2);  // -> W4t after megaB
  bf16_t* iMt16 = (bf16_t*)alloc((size_t)NDIM * NDIM * 2);
  bf16_t* H16   = (bf16_t*)alloc((size_t)NDIM * NDIM * 2);  // -> W2t after megaA
  bf16_t* Wrm   = (bf16_t*)alloc((size_t)NDIM * NDIM * 2);
  bf16_t* Wt    = (bf16_t*)alloc((size_t)NDIM * NDIM * 2);
  bf16_t* y16   = (bf16_t*)alloc(BSN * 2);
  bf16_t* yMF16 = (bf16_t*)alloc(BSN * 2);
  bf16_t* c16   = (bf16_t*)alloc(BSN * 2);
  bf16_t* c2_16 = (bf16_t*)alloc(BSN * 2);
  float*  c32   = (float*)alloc(BSN * 4);
  float*  c2_32 = (float*)alloc(BSN * 4);
  float*  c4_32 = (float*)alloc(BSN * 4);
  bf16_t* z0    = (bf16_t*)alloc(2 * BSN * 2);
  bf16_t* zA    = (bf16_t*)alloc(4 * BSN * 2);
  bf16_t* zB    = (bf16_t*)alloc(4 * BSN * 2);
  bf16_t* W2t   = H16;
  bf16_t* W2rm  = U16;
  bf16_t* W4t   = Dt16;

  prep<<<3072, 512, 0, stream>>>(H, U, Dinv, invM, y, H16, U16, Dt16, iMt16, y16, traj);
  megaA<<<384, 512, 0, stream>>>(U16, iMt16, y16, H16, Wrm, yMF16);
  megaB<<<1280, 512, 0, stream>>>(Wrm, yMF16, iMt16, Dt16, Wt, c32, c16, z0);
  megaC<<<512, 512, 0, stream>>>(Wt, Wrm, z0, c16, c32, W2t, traj + BSN, z0 + BSN, c2_32, c2_16);
  megaD<<<1408, 512, 0, stream>>>(W2t, z0, c2_16, c2_32, W2rm, traj + 2 * BSN, traj + 3 * BSN,
                                  zA, c4_32);
  megaE<<<512, 512, 0, stream>>>(W2t, W2rm, zA, c2_32, W4t, traj + 4 * BSN, traj + 5 * BSN, zA);

  bf16_t* zcur = zA;
  bf16_t* znxt = zB;
  for (int g = 0; g < 5; ++g) {
    float* sfin = (g == 4) ? s_final : nullptr;
    quad_step<<<512, 512, 0, stream>>>(zcur, W4t, c4_32, traj + (size_t)(6 + 4 * g) * BSN,
                                       znxt, sfin);
    bf16_t* tmp = zcur; zcur = znxt; znxt = tmp;
  }
}

// Round 8
// 385.237 us; speedup vs baseline: 1.1670x; 1.0102x over previous
//
#include <hip/hip_runtime.h>
#include <hip/hip_bf16.h>

#define NDIM 2048
#define BS   64
#define NM4  (NDIM * NDIM / 4)
#define BSN  ((size_t)BS * NDIM)
#define SMEM_BYTES 69632   // wgemm: 4x16KB pipeline (+ 34.8KB transpose reuse); skinny: 64KB+4KB

typedef __bf16 bf16_t;
typedef __bf16 bf16x4 __attribute__((ext_vector_type(4)));
typedef __bf16 bf16x8 __attribute__((ext_vector_type(8)));
typedef float  f32x4  __attribute__((ext_vector_type(4)));

// Async global->LDS, 16 B per lane.  LDS dest = wave-uniform base + lane*16.
__device__ __forceinline__ void gload16(const void* g, void* lds) {
  __builtin_amdgcn_global_load_lds(
      (const __attribute__((address_space(1))) void*)g,
      (__attribute__((address_space(3))) void*)lds, 16, 0, 0);
}
// 32-bit LDS byte offset of a generic pointer into __shared__.
__device__ __forceinline__ uint32_t lds_off(void* p) {
  return (uint32_t)(uintptr_t)(__attribute__((address_space(3))) void*)p;
}

#define WB4 asm volatile("s_waitcnt vmcnt(4)\n\ts_barrier" ::: "memory")
#define WB2 asm volatile("s_waitcnt vmcnt(2)\n\ts_barrier" ::: "memory")
#define WB0 asm volatile("s_waitcnt vmcnt(0)\n\ts_barrier" ::: "memory")

// ---------------------------------------------------------------------------
// prep (512 thr, 3072 blocks): b<1024 convert H,U (+y, traj0); else 64x64
// fp32->bf16 vectorized transposes of Dinv, invM.
// ---------------------------------------------------------------------------
__global__ __launch_bounds__(512) void prep(
    const float* __restrict__ H, const float* __restrict__ U,
    const float* __restrict__ Dinv, const float* __restrict__ invM,
    const float* __restrict__ y,
    bf16_t* __restrict__ H16, bf16_t* __restrict__ U16,
    bf16_t* __restrict__ Dt, bf16_t* __restrict__ iMt,
    bf16_t* __restrict__ y16, float* __restrict__ traj0) {
  __shared__ bf16_t tile[64][72];
  int b = blockIdx.x, tid = threadIdx.x;
  if (b < 1024) {
#pragma unroll
    for (int i = 0; i < 4; ++i) {
      int idx = b * 2048 + i * 512 + tid;
      const float* src = (idx < NM4) ? H : U;
      bf16_t* dst = (idx < NM4) ? H16 : U16;
      int j = (idx < NM4) ? idx : idx - NM4;
      float4 v = ((const float4*)src)[j];
      bf16x4 o = {(bf16_t)v.x, (bf16_t)v.y, (bf16_t)v.z, (bf16_t)v.w};
      ((bf16x4*)dst)[j] = o;
    }
    int yi = b * 512 + tid;
    if (yi < BS * NDIM / 4) {
      float4 w = ((const float4*)y)[yi];
      bf16x4 o2 = {(bf16_t)w.x, (bf16_t)w.y, (bf16_t)w.z, (bf16_t)w.w};
      ((bf16x4*)y16)[yi] = o2;
      ((float4*)traj0)[yi] = make_float4(0.f, 0.f, 0.f, 0.f);
    }
  } else {
    int id = b - 1024;
    const float* src = (id < 1024) ? Dinv : invM;
    bf16_t* dst = (id < 1024) ? Dt : iMt;
    id &= 1023;
    int bx = id & 31, by = id >> 5;
    int r = tid >> 3, c8 = (tid & 7) * 8;
    const float* sp = src + (size_t)(by * 64 + r) * NDIM + bx * 64 + c8;
    float4 v0 = *(const float4*)sp;
    float4 v1 = *(const float4*)(sp + 4);
    bf16_t* t = &tile[r][c8];
    t[0] = (bf16_t)v0.x; t[1] = (bf16_t)v0.y; t[2] = (bf16_t)v0.z; t[3] = (bf16_t)v0.w;
    t[4] = (bf16_t)v1.x; t[5] = (bf16_t)v1.y; t[6] = (bf16_t)v1.z; t[7] = (bf16_t)v1.w;
    __syncthreads();
    bf16x8 o;
#pragma unroll
    for (int j = 0; j < 8; ++j) o[j] = tile[c8 + j][r];
    *(bf16x8*)(dst + (size_t)(bx * 64 + r) * NDIM + by * 64 + c8) = o;
  }
}

// ---------------------------------------------------------------------------
// wgemm v4: 2048^3 NT GEMM, 512 thr, 128x128 tile, BK=32, 64 chunks, 4-stage
// async pipeline.  KEY: fragment loads are raw asm ds_read_b128 (invisible to
// the compiler's waitcnt pass, so it cannot insert vmcnt(0) drains); data
// readiness enforced by an lgkmcnt(0) asm that redefines the fragment regs.
// Optional transposed store Ct via LDS round-trip in the freed buffers.
// ---------------------------------------------------------------------------
__device__ __forceinline__ void wgemm_role(
    const bf16_t* __restrict__ A, const bf16_t* __restrict__ Bt,
    bf16_t* __restrict__ C, bf16_t* __restrict__ Ct, int blk, char* smem) {
  int tid = threadIdx.x, lane = tid & 63, wave = tid >> 6;
  int m0 = (blk >> 4) * 128, n0 = (blk & 15) * 128;
  int rl = lane & 15, q = lane >> 4;
  const bf16_t* Ag = A  + (size_t)(m0 + wave * 16 + rl) * NDIM + q * 8;
  const bf16_t* Bg = Bt + (size_t)(n0 + wave * 16 + rl) * NDIM + q * 8;
  char* ldsA = smem + wave * 1024;          // staging slice (this wave) + stage*16384
  char* ldsB = smem + 8192 + wave * 1024;

  int wr2 = (wave & 3) * 2, wc4 = (wave >> 2) * 4;
  uint32_t abase = lds_off(smem) + wr2 * 1024 + lane * 16;
  uint32_t bbase = lds_off(smem) + 8192 + wc4 * 1024 + lane * 16;

  f32x4 acc[2][4];
#pragma unroll
  for (int i = 0; i < 2; ++i)
#pragma unroll
    for (int j = 0; j < 4; ++j) acc[i][j] = (f32x4){0.f, 0.f, 0.f, 0.f};

#define STAGE(s)                                  \
  {                                               \
    int _b = (s) & 3, _k = (s) * 32;              \
    gload16(Ag + _k, ldsA + _b * 16384);          \
    gload16(Bg + _k, ldsB + _b * 16384);          \
  }
#define COMPUTE(bb)                                                            \
  {                                                                            \
    uint32_t av = abase + (bb) * 16384;                                        \
    uint32_t bv = bbase + (bb) * 16384;                                        \
    bf16x8 af0, af1, bg0, bg1, bg2, bg3;                                       \
    asm volatile("ds_read_b128 %0, %1"             : "=v"(af0) : "v"(av));     \
    asm volatile("ds_read_b128 %0, %1 offset:1024" : "=v"(af1) : "v"(av));     \
    asm volatile("ds_read_b128 %0, %1"             : "=v"(bg0) : "v"(bv));     \
    asm volatile("ds_read_b128 %0, %1 offset:1024" : "=v"(bg1) : "v"(bv));     \
    asm volatile("ds_read_b128 %0, %1 offset:2048" : "=v"(bg2) : "v"(bv));     \
    asm volatile("ds_read_b128 %0, %1 offset:3072" : "=v"(bg3) : "v"(bv));     \
    asm volatile("s_waitcnt lgkmcnt(0)"                                        \
                 : "+v"(af0), "+v"(af1), "+v"(bg0), "+v"(bg1), "+v"(bg2),      \
                   "+v"(bg3));                                                 \
    acc[0][0] = __builtin_amdgcn_mfma_f32_16x16x32_bf16(af0, bg0, acc[0][0], 0, 0, 0); \
    acc[0][1] = __builtin_amdgcn_mfma_f32_16x16x32_bf16(af0, bg1, acc[0][1], 0, 0, 0); \
    acc[0][2] = __builtin_amdgcn_mfma_f32_16x16x32_bf16(af0, bg2, acc[0][2], 0, 0, 0); \
    acc[0][3] = __builtin_amdgcn_mfma_f32_16x16x32_bf16(af0, bg3, acc[0][3], 0, 0, 0); \
    acc[1][0] = __builtin_amdgcn_mfma_f32_16x16x32_bf16(af1, bg0, acc[1][0], 0, 0, 0); \
    acc[1][1] = __builtin_amdgcn_mfma_f32_16x16x32_bf16(af1, bg1, acc[1][1], 0, 0, 0); \
    acc[1][2] = __builtin_amdgcn_mfma_f32_16x16x32_bf16(af1, bg2, acc[1][2], 0, 0, 0); \
    acc[1][3] = __builtin_amdgcn_mfma_f32_16x16x32_bf16(af1, bg3, acc[1][3], 0, 0, 0); \
  }

  STAGE(0); STAGE(1); STAGE(2);
  int s = 3;
#pragma unroll 1
  for (int k = 0; k < 60; k += 4) {
    WB4; STAGE(s); ++s; COMPUTE(0);
    WB4; STAGE(s); ++s; COMPUTE(1);
    WB4; STAGE(s); ++s; COMPUTE(2);
    WB4; STAGE(s); ++s; COMPUTE(3);
  }
  WB4; STAGE(63); COMPUTE(0);   // chunk 60
  WB4; COMPUTE(1);              // chunk 61
  WB2; COMPUTE(2);              // chunk 62
  WB0; COMPUTE(3);              // chunk 63
#undef STAGE
#undef COMPUTE

  // normal-orientation store (C[m][n])
#pragma unroll
  for (int i = 0; i < 2; ++i)
#pragma unroll
    for (int j = 0; j < 4; ++j)
#pragma unroll
      for (int r = 0; r < 4; ++r)
        C[(size_t)(m0 + (wr2 + i) * 16 + q * 4 + r) * NDIM + n0 + (wc4 + j) * 16 + rl] =
            (bf16_t)acc[i][j][r];

  // optional transposed store (Ct[n][m]) via LDS round-trip
  if (Ct) {
    __syncthreads();
    bf16_t (*tileT)[136] = (bf16_t(*)[136])smem;   // 128 x 136 x 2 B = 34.8 KB
#pragma unroll
    for (int i = 0; i < 2; ++i)
#pragma unroll
      for (int j = 0; j < 4; ++j)
#pragma unroll
        for (int r = 0; r < 4; ++r)
          tileT[(wc4 + j) * 16 + rl][(wr2 + i) * 16 + q * 4 + r] = (bf16_t)acc[i][j][r];
    __syncthreads();
#pragma unroll
    for (int t = 0; t < 4; ++t) {
      int v = t * 512 + tid, row = v >> 4, c8 = (v & 15) * 8;
      *(bf16x8*)(Ct + (size_t)(n0 + row) * NDIM + m0 + c8) = *(bf16x8*)&tileT[row][c8];
    }
  }
}

// ---------------------------------------------------------------------------
// skinny v3: C[64,16] = add + sign*(A[64,2048] @ Bt^T cols n0..+15).
// Panel (64 KB, fragment order) staged async; waves 0-3 K-half0 / 4-7 K-half1;
// 8 round-robin accumulators; LDS f32 reduction joins halves.
// ---------------------------------------------------------------------------
__device__ __forceinline__ void skinny_role(
    const bf16_t* __restrict__ A, const bf16_t* __restrict__ Bt, int n0, char* smem,
    const float* __restrict__ add, float sign,
    float* o32, float* o32b, bf16_t* o16) {
  int tid = threadIdx.x, lane = tid & 63, wave = tid >> 6;
  int rl = lane & 15, q = lane >> 4;
#pragma unroll
  for (int i = 0; i < 8; ++i) {
    const bf16_t* g = Bt + (size_t)(n0 + rl) * NDIM + (i * 8 + wave) * 32 + q * 8;
    gload16(g, smem + (size_t)(i * 512 + wave * 64) * 16);
  }
  __syncthreads();

  int ms = (wave & 3) * 16, kh = wave >> 2;
  const bf16x8* Ap = (const bf16x8*)(A + (size_t)(ms + rl) * NDIM) + q + kh * 128;
  const bf16x8* Bp = (const bf16x8*)smem + lane + kh * 2048;

  f32x4 acc[8];
#pragma unroll
  for (int i = 0; i < 8; ++i) acc[i] = (f32x4){0.f, 0.f, 0.f, 0.f};
#pragma unroll
  for (int c = 0; c < 32; ++c)
    acc[c & 7] = __builtin_amdgcn_mfma_f32_16x16x32_bf16(Ap[c * 4], Bp[c * 64], acc[c & 7], 0, 0, 0);
  f32x4 s = ((acc[0] + acc[1]) + (acc[2] + acc[3])) + ((acc[4] + acc[5]) + (acc[6] + acc[7]));

  f32x4* red = (f32x4*)(smem + 65536);
  if (wave >= 4) red[(wave & 3) * 64 + lane] = s;
  __syncthreads();
  if (wave < 4) {
    s += red[wave * 64 + lane];
    int mrow = ms + q * 4, col = n0 + rl;
#pragma unroll
    for (int r = 0; r < 4; ++r) {
      size_t o = (size_t)(mrow + r) * NDIM + col;
      float v = sign * s[r];
      if (add) v += add[o];
      if (o32)  o32[o]  = v;
      if (o32b) o32b[o] = v;
      if (o16)  o16[o]  = (bf16_t)v;
    }
  }
}

// --------------------------- mega nodes (512 thr) --------------------------
// A: W = U@invM, dual store Wrm+Wt (256 wgemm) || yMF = y@H^T (128 skinny)
__global__ __launch_bounds__(512, 4) void megaA(
    const bf16_t* __restrict__ U16, const bf16_t* __restrict__ iMt16,
    const bf16_t* __restrict__ y16, const bf16_t* __restrict__ H16,
    bf16_t* __restrict__ Wrm, bf16_t* __restrict__ Wt, bf16_t* __restrict__ yMF16) {
  __shared__ char smem[SMEM_BYTES];
  int b = blockIdx.x;
  if (b < 256) wgemm_role(U16, iMt16, Wrm, Wt, b, smem);
  else         skinny_role(y16, H16, (b - 256) * 16, smem, nullptr, 1.f, nullptr, nullptr, yMF16);
}

// B (light): c = yMF@invM (128) || x0 = yMF@Dinv (128 -> z0)
__global__ __launch_bounds__(512, 4) void megaB(
    const bf16_t* __restrict__ yMF16, const bf16_t* __restrict__ iMt16,
    const bf16_t* __restrict__ Dt16,
    float* __restrict__ c32, bf16_t* __restrict__ c16, bf16_t* __restrict__ z0) {
  __shared__ char smem[SMEM_BYTES];
  int b = blockIdx.x;
  if (b < 128) skinny_role(yMF16, iMt16, b * 16, smem, nullptr, 1.f, c32, nullptr, c16);
  else         skinny_role(yMF16, Dt16, (b - 128) * 16, smem, nullptr, 1.f, nullptr, nullptr, z0);
}

// C: W2 = NT(Wt,Wrm), dual store W2t+W2rm (256) || x1 (128 -> traj[1], z0+BSN)
//    || c2 (128)
__global__ __launch_bounds__(512, 4) void megaC(
    const bf16_t* __restrict__ Wt, const bf16_t* __restrict__ Wrm,
    const bf16_t* __restrict__ z0, const bf16_t* __restrict__ c16,
    const float* __restrict__ c32,
    bf16_t* __restrict__ W2t, bf16_t* __restrict__ W2rm,
    float* __restrict__ traj1, bf16_t* __restrict__ z0b,
    float* __restrict__ c2_32, bf16_t* __restrict__ c2_16) {
  __shared__ char smem[SMEM_BYTES];
  int b = blockIdx.x;
  if (b < 256)      wgemm_role(Wt, Wrm, W2t, W2rm, b, smem);
  else if (b < 384) skinny_role(z0, Wt, (b - 256) * 16, smem, c32, -1.f, traj1, nullptr, z0b);
  else              skinny_role(c16, Wt, (b - 384) * 16, smem, c32, -1.f, c2_32, nullptr, c2_16);
}

// D (light): x2 (128 -> traj[2], zA0) || x3 (128 -> traj[3], zA1) || c4 (128)
__global__ __launch_bounds__(512, 4) void megaD(
    const bf16_t* __restrict__ W2t, const bf16_t* __restrict__ z0,
    const bf16_t* __restrict__ c2_16, const float* __restrict__ c2_32,
    float* __restrict__ traj2, float* __restrict__ traj3,
    bf16_t* __restrict__ zA, float* __restrict__ c4_32) {
  __shared__ char smem[SMEM_BYTES];
  int b = blockIdx.x;
  if (b < 128)      skinny_role(z0, W2t, b * 16, smem, c2_32, 1.f, traj2, nullptr, zA);
  else if (b < 256) skinny_role(z0 + BSN, W2t, (b - 128) * 16, smem, c2_32, 1.f, traj3, nullptr, zA + BSN);
  else              skinny_role(c2_16, W2t, (b - 256) * 16, smem, c2_32, 1.f, c4_32, nullptr, nullptr);
}

// E: W4t = NT(W2t,W2rm) (256) || x4 (128 -> traj[4], zA2) || x5 (128 -> traj[5], zA3)
__global__ __launch_bounds__(512, 4) void megaE(
    const bf16_t* __restrict__ W2t, const bf16_t* __restrict__ W2rm,
    const bf16_t* __restrict__ zA_in, const float* __restrict__ c2_32,
    bf16_t* __restrict__ W4t, float* __restrict__ traj4, float* __restrict__ traj5,
    bf16_t* __restrict__ zA) {
  __shared__ char smem[SMEM_BYTES];
  int b = blockIdx.x;
  if (b < 256)      wgemm_role(W2t, W2rm, W4t, nullptr, b, smem);
  else if (b < 384) skinny_role(zA_in, W2t, (b - 256) * 16, smem, c2_32, 1.f, traj4, nullptr, zA + 2 * BSN);
  else              skinny_role(zA_in + BSN, W2t, (b - 384) * 16, smem, c2_32, 1.f, traj5, nullptr, zA + 3 * BSN);
}

// Quad step: 4 chains x_{k+4} = c4 + x_k@W4.  512 blocks: chain b&3, panel b>>2.
__global__ __launch_bounds__(512, 4) void quad_step(
    const bf16_t* __restrict__ zin, const bf16_t* __restrict__ W4t,
    const float* __restrict__ c4_32, float* __restrict__ trajb,
    bf16_t* __restrict__ zout, float* __restrict__ sfin) {
  __shared__ char smem[SMEM_BYTES];
  int b = blockIdx.x, ci = b & 3, p = b >> 2;
  skinny_role(zin + (size_t)ci * BSN, W4t, p * 16, smem, c4_32, 1.f,
              trajb + (size_t)ci * BSN, (ci == 3) ? sfin : nullptr,
              zout + (size_t)ci * BSN);
}

// ---------------------------------------------------------------------------
// Host driver: 11 graph nodes.
// ---------------------------------------------------------------------------
extern "C" void kernel_launch(void* const* d_in, const int* in_sizes, int n_in,
                              void* d_out, int out_size, void* d_ws, size_t ws_size,
                              hipStream_t stream) {
  const float* y    = (const float*)d_in[2];
  const float* H    = (const float*)d_in[3];
  const float* Dinv = (const float*)d_in[4];
  const float* U    = (const float*)d_in[5];
  const float* invM = (const float*)d_in[6];

  float* out     = (float*)d_out;
  float* s_final = out;
  float* traj    = out + BSN;

  char* ws = (char*)d_ws;
  size_t off = 0;
  auto alloc = [&](size_t bytes) -> void* {
    void* p = ws + off;
    off += (bytes + 255) & ~(size_t)255;
    return p;
  };
  bf16_t* U16   = (bf16_t*)alloc((size_t)NDIM * NDIM * 2);  // -> W2rm after megaA
  bf16_t* Dt16  = (bf16_t*)alloc((size_t)NDIM * NDIM * 2);  // -> W4t after megaB
  bf16_t* iMt16 = (bf16_t*)alloc((size_t)NDIM * NDIM * 2);
  bf16_t* H16   = (bf16_t*)alloc((size_t)NDIM * NDIM * 2);  // -> W2t after megaA
  bf16_t* Wrm   = (bf16_t*)alloc((size_t)NDIM * NDIM * 2);
  bf16_t* Wt    = (bf16_t*)alloc((size_t)NDIM * NDIM * 2);
  bf16_t* y16   = (bf16_t*)alloc(BSN * 2);
  bf16_t* yMF16 = (bf16_t*)alloc(BSN * 2);
  bf16_t* c16   = (bf16_t*)alloc(BSN * 2);
  bf16_t* c2_16 = (bf16_t*)alloc(BSN * 2);
  float*  c32   = (float*)alloc(BSN * 4);
  float*  c2_32 = (float*)alloc(BSN * 4);
  float*  c4_32 = (float*)alloc(BSN * 4);
  bf16_t* z0    = (bf16_t*)alloc(2 * BSN * 2);  // x0, x1
  bf16_t* zA    = (bf16_t*)alloc(4 * BSN * 2);  // chains x2..x5
  bf16_t* zB    = (bf16_t*)alloc(4 * BSN * 2);
  bf16_t* W2t   = H16;   // H16 dead after megaA
  bf16_t* W2rm  = U16;   // U16 dead after megaA
  bf16_t* W4t   = Dt16;  // Dt16 dead after megaB

  prep<<<3072, 512, 0, stream>>>(H, U, Dinv, invM, y, H16, U16, Dt16, iMt16, y16, traj);
  megaA<<<384, 512, 0, stream>>>(U16, iMt16, y16, H16, Wrm, Wt, yMF16);
  megaB<<<256, 512, 0, stream>>>(yMF16, iMt16, Dt16, c32, c16, z0);
  megaC<<<512, 512, 0, stream>>>(Wt, Wrm, z0, c16, c32, W2t, W2rm,
                                 traj + BSN, z0 + BSN, c2_32, c2_16);
  megaD<<<384, 512, 0, stream>>>(W2t, z0, c2_16, c2_32, traj + 2 * BSN, traj + 3 * BSN,
                                 zA, c4_32);
  megaE<<<512, 512, 0, stream>>>(W2t, W2rm, zA, c2_32, W4t, traj + 4 * BSN, traj + 5 * BSN, zA);

  bf16_t* zcur = zA;
  bf16_t* znxt = zB;
  for (int g = 0; g < 5; ++g) {
    float* sfin = (g == 4) ? s_final : nullptr;
    quad_step<<<512, 512, 0, stream>>>(zcur, W4t, c4_32, traj + (size_t)(6 + 4 * g) * BSN,
                                       znxt, sfin);
    bf16_t* tmp = zcur; zcur = znxt; znxt = tmp;
  }
}